// Round 3
// baseline (237.210 us; speedup 1.0000x reference)
//
#include <hip/hip_runtime.h>

#define BB 1024
#define DD 512
#define RT 128   // rows (b) per block
#define CT 128   // cols (j) per block
#define KT 16    // i-depth per block
#define NIC (DD / KT)               // 32 i-chunks
#define NP ((DD / CT) * NIC)        // 128 partials per b

// out[b] = ||x_dot[b]||^2 + t[b]^2,  t[b] = sum_{i,j} x_dot[b,i] W[i,j] x[b,j]
// k1: block (rg,jc,ic) computes partial_t[b] over its (i,j) rectangle,
//     writes ws[p][b], p = jc*NIC+ic. Deterministic (no atomics/memset).
__global__ __launch_bounds__(256, 4) void stm_main_kernel(
    const float* __restrict__ x, const float* __restrict__ xdot,
    const float* __restrict__ W, float* __restrict__ ws_t) {
  __shared__ float xd_s[RT][KT];   // 8 KB, b-major (no transpose needed)
  __shared__ float w_s[KT][CT];    // 8 KB

  const int tid = threadIdx.x;
  const int b0 = blockIdx.x * RT;
  const int j0 = blockIdx.y * CT;
  const int i0 = blockIdx.z * KT;
  const int tb = tid >> 4;    // 0..15 -> rows b0 + tb*8 + r, r=0..7
  const int tj = tid & 15;    // 0..15 -> cols j0 + tj*8 + c, c=0..7

  // Stage xd rows: 128 rows x 16 cols = 512 float4, 2 per thread (coalesced,
  // direct copy; LDS write banks 2-way at worst = free).
#pragma unroll
  for (int v = 0; v < 2; ++v) {
    const int idx = tid + v * 256;
    const int row = idx >> 2, c4 = idx & 3;
    *(float4*)&xd_s[row][c4 * 4] =
        *(const float4*)(xdot + (size_t)(b0 + row) * DD + i0 + c4 * 4);
  }
  // Stage W tile: 16 x 128 = 512 float4, 2 per thread.
#pragma unroll
  for (int v = 0; v < 2; ++v) {
    const int idx = tid + v * 256;
    const int ii = idx >> 5, jj4 = idx & 31;
    *(float4*)&w_s[ii][jj4 * 4] =
        *(const float4*)(W + (size_t)(i0 + ii) * DD + j0 + jj4 * 4);
  }
  __syncthreads();

  // acc[r][c] = sum_i xd[b0+tb*8+r, i] * W[i, j0+tj*8+c]
  float acc[8][8] = {};
#pragma unroll
  for (int i2 = 0; i2 < KT; i2 += 2) {
    float2 xd[8];   // xd rows, 2 i-steps each (b64 reads, 4 unique addrs/wave)
#pragma unroll
    for (int r = 0; r < 8; ++r)
      xd[r] = *(const float2*)&xd_s[tb * 8 + r][i2];
#pragma unroll
    for (int s = 0; s < 2; ++s) {
      const float4 wlo = *(const float4*)&w_s[i2 + s][tj * 8];
      const float4 whi = *(const float4*)&w_s[i2 + s][tj * 8 + 4];
#pragma unroll
      for (int r = 0; r < 8; ++r) {
        const float a = s ? xd[r].y : xd[r].x;
        acc[r][0] += a * wlo.x; acc[r][1] += a * wlo.y;
        acc[r][2] += a * wlo.z; acc[r][3] += a * wlo.w;
        acc[r][4] += a * whi.x; acc[r][5] += a * whi.y;
        acc[r][6] += a * whi.z; acc[r][7] += a * whi.w;
      }
    }
  }

  // Contract with x over this thread's 8 j's (coalesced 512B-per-group loads).
  float tp[8];
#pragma unroll
  for (int r = 0; r < 8; ++r) {
    const float* xr = x + (size_t)(b0 + tb * 8 + r) * DD + j0 + tj * 8;
    const float4 xlo = *(const float4*)xr;
    const float4 xhi = *(const float4*)(xr + 4);
    tp[r] = acc[r][0] * xlo.x + acc[r][1] * xlo.y +
            acc[r][2] * xlo.z + acc[r][3] * xlo.w +
            acc[r][4] * xhi.x + acc[r][5] * xhi.y +
            acc[r][6] * xhi.z + acc[r][7] * xhi.w;
  }
  // Reduce over the 16 tj lanes (xor < 16 stays within the tj group).
#pragma unroll
  for (int off = 8; off >= 1; off >>= 1) {
#pragma unroll
    for (int r = 0; r < 8; ++r) tp[r] += __shfl_xor(tp[r], off);
  }
  if (tj == 0) {
    const int p = blockIdx.y * NIC + blockIdx.z;
    float* dst = ws_t + (size_t)p * BB + b0 + tb * 8;
    *(float4*)(dst + 0) = make_float4(tp[0], tp[1], tp[2], tp[3]);
    *(float4*)(dst + 4) = make_float4(tp[4], tp[5], tp[6], tp[7]);
  }
}

// k2: one wave per b. out[b] = ||x_dot[b]||^2 + (sum_p ws[p][b])^2.
__global__ __launch_bounds__(256) void stm_final_kernel(
    const float* __restrict__ xdot, const float* __restrict__ ws_t,
    float* __restrict__ out) {
  const int tid = threadIdx.x;
  const int wv = tid >> 6, ln = tid & 63;
  const int b = blockIdx.x * 4 + wv;
  const float4* xd4 = (const float4*)(xdot + (size_t)b * DD);  // 128 f4/row
  const float4 a = xd4[ln];
  const float4 c = xd4[64 + ln];
  float n = a.x * a.x + a.y * a.y + a.z * a.z + a.w * a.w +
            c.x * c.x + c.y * c.y + c.z * c.z + c.w * c.w;
  float t = ws_t[(size_t)ln * BB + b] + ws_t[(size_t)(ln + 64) * BB + b];
#pragma unroll
  for (int off = 32; off >= 1; off >>= 1) {
    n += __shfl_xor(n, off);
    t += __shfl_xor(t, off);
  }
  if (ln == 0) out[b] = n + t * t;
}

extern "C" void kernel_launch(void* const* d_in, const int* in_sizes, int n_in,
                              void* d_out, int out_size, void* d_ws, size_t ws_size,
                              hipStream_t stream) {
  const float* x    = (const float*)d_in[0];
  const float* xdot = (const float*)d_in[1];
  const float* W    = (const float*)d_in[2];
  float* ws = (float*)d_ws;   // NP * BB floats = 512 KB of t partials
  float* out = (float*)d_out;

  dim3 g1(BB / RT, DD / CT, NIC);  // (8, 4, 32) = 1024 blocks
  stm_main_kernel<<<g1, 256, 0, stream>>>(x, xdot, W, ws);
  stm_final_kernel<<<BB / 4, 256, 0, stream>>>(xdot, ws, out);
}

// Round 4
// 68.826 us; speedup vs baseline: 3.4465x; 3.4465x over previous
//
#include <hip/hip_runtime.h>

#define BB 1024
#define DD 512
#define BTILE 32     // batch rows per block
#define JTILE 128    // j columns per block
#define ICH 64       // i depth per block
#define NIC (DD / ICH)              // 8 i-chunks
#define NP ((DD / JTILE) * NIC)     // 32 partials per b

// out[b] = ||x_dot[b]||^2 + t[b]^2,  t[b] = sum_{i,j} x_dot[b,i] W[i,j] x[b,j]
// k1: block (rg,jc,ic) computes the partial of t[b] over its (i,j) rectangle
//     and stores it to ws[p][b], p = jc*NIC+ic. Deterministic, no atomics.
// 4x4 per-thread register tile (~50 VGPR — R3's 8x8 tile spilled to scratch,
// 573 MB HBM traffic; keep the tile small).
__global__ __launch_bounds__(256, 4) void stm_main_kernel(
    const float* __restrict__ x, const float* __restrict__ xdot,
    const float* __restrict__ W, float* __restrict__ ws_t) {
  __shared__ float xd_t[ICH][BTILE];   // 8 KB, transposed x_dot chunk [i][b]
  __shared__ float w_s[ICH][JTILE];    // 32 KB W tile

  const int tid = threadIdx.x;
  const int b0 = blockIdx.x * BTILE;
  const int j0 = blockIdx.y * JTILE;
  const int i0 = blockIdx.z * ICH;
  const int tb = tid >> 5;   // 0..7  -> rows b0 + 4*tb .. +3
  const int tj = tid & 31;   // 0..31 -> cols j0 + 4*tj .. +3

  // Stage x_dot chunk transposed: rows b0..b0+31, cols i0..i0+63.
  // Scalar writes hit bank = row -> 2-way at worst (free).
  {
    const int row = tid & 31;
    const int f4 = tid >> 5;             // 0..7
    const float4* src = (const float4*)(xdot + (size_t)(b0 + row) * DD + i0);
#pragma unroll
    for (int p = 0; p < 2; ++p) {
      const int c4 = f4 + p * 8;         // 0..15
      float4 v = src[c4];
      const int c = c4 * 4;
      xd_t[c + 0][row] = v.x; xd_t[c + 1][row] = v.y;
      xd_t[c + 2][row] = v.z; xd_t[c + 3][row] = v.w;
    }
  }
  // Stage W tile: rows i0..i0+63, cols j0..j0+127 (2048 float4 / 256 thr).
  {
#pragma unroll
    for (int v = 0; v < 8; ++v) {
      const int f4 = tid + v * 256;
      const int ii = f4 >> 5, jj4 = f4 & 31;
      *((float4*)&w_s[ii][jj4 * 4]) =
          ((const float4*)(W + (size_t)(i0 + ii) * DD + j0))[jj4];
    }
  }
  __syncthreads();

  // acc[r][c] = sum_i xd[b0+4tb+r, i] * W[i, j0+4tj+c]
  float acc[4][4] = {};
#pragma unroll
  for (int i = 0; i < ICH; ++i) {
    const float4 xd = *(const float4*)&xd_t[i][tb * 4];  // 8 uniq addrs/wave
    const float4 w  = *(const float4*)&w_s[i][tj * 4];
    acc[0][0] += xd.x * w.x; acc[0][1] += xd.x * w.y;
    acc[0][2] += xd.x * w.z; acc[0][3] += xd.x * w.w;
    acc[1][0] += xd.y * w.x; acc[1][1] += xd.y * w.y;
    acc[1][2] += xd.y * w.z; acc[1][3] += xd.y * w.w;
    acc[2][0] += xd.z * w.x; acc[2][1] += xd.z * w.y;
    acc[2][2] += xd.z * w.z; acc[2][3] += xd.z * w.w;
    acc[3][0] += xd.w * w.x; acc[3][1] += xd.w * w.y;
    acc[3][2] += xd.w * w.z; acc[3][3] += xd.w * w.w;
  }

  // Contract with x over this thread's 4 j's, reduce over the 32 tj lanes.
  float tp[4];
#pragma unroll
  for (int r = 0; r < 4; ++r) {
    const float4 xv =
        ((const float4*)(x + (size_t)(b0 + tb * 4 + r) * DD + j0))[tj];
    tp[r] = acc[r][0] * xv.x + acc[r][1] * xv.y +
            acc[r][2] * xv.z + acc[r][3] * xv.w;
  }
#pragma unroll
  for (int off = 16; off >= 1; off >>= 1) {
#pragma unroll
    for (int r = 0; r < 4; ++r) tp[r] += __shfl_xor(tp[r], off);
  }
  if (tj == 0) {
    const int p = blockIdx.y * NIC + blockIdx.z;   // 0..31
    *(float4*)(ws_t + (size_t)p * BB + b0 + tb * 4) =
        make_float4(tp[0], tp[1], tp[2], tp[3]);
  }
}

// k2: one wave per b. out[b] = ||x_dot[b]||^2 + (sum_p ws[p][b])^2.
__global__ __launch_bounds__(256) void stm_final_kernel(
    const float* __restrict__ xdot, const float* __restrict__ ws_t,
    float* __restrict__ out) {
  const int tid = threadIdx.x;
  const int wv = tid >> 6, ln = tid & 63;
  const int b = blockIdx.x * 4 + wv;
  const float4* xd4 = (const float4*)(xdot + (size_t)b * DD);  // 128 f4/row
  const float4 a = xd4[ln];
  const float4 c = xd4[64 + ln];
  float n = a.x * a.x + a.y * a.y + a.z * a.z + a.w * a.w +
            c.x * c.x + c.y * c.y + c.z * c.z + c.w * c.w;
  float t = (ln < NP) ? ws_t[(size_t)ln * BB + b] : 0.f;
#pragma unroll
  for (int off = 32; off >= 1; off >>= 1) {
    n += __shfl_xor(n, off);
    t += __shfl_xor(t, off);
  }
  if (ln == 0) out[b] = n + t * t;
}

extern "C" void kernel_launch(void* const* d_in, const int* in_sizes, int n_in,
                              void* d_out, int out_size, void* d_ws, size_t ws_size,
                              hipStream_t stream) {
  const float* x    = (const float*)d_in[0];
  const float* xdot = (const float*)d_in[1];
  const float* W    = (const float*)d_in[2];
  float* ws = (float*)d_ws;   // NP * BB floats = 128 KB of t partials
  float* out = (float*)d_out;

  dim3 g1(BB / BTILE, DD / JTILE, NIC);  // (32, 4, 8) = 1024 blocks
  stm_main_kernel<<<g1, 256, 0, stream>>>(x, xdot, W, ws);
  stm_final_kernel<<<BB / 4, 256, 0, stream>>>(xdot, ws, out);
}

// Round 5
// 68.730 us; speedup vs baseline: 3.4513x; 1.0014x over previous
//
#include <hip/hip_runtime.h>

#define BB 1024
#define DD 512
#define BTILE 32     // batch rows per block
#define JTILE 128    // j columns per block
#define ICH 64       // i depth per block
#define NIC (DD / ICH)              // 8 i-chunks
#define NTP ((DD / JTILE) * NIC)    // 32 t-partials per b
#define NNP (NIC * 4)               // 32 norm-partials per b (ic x wave)
// ws layout: rows 0..31 = t partials, rows 32..63 = norm partials; [row][b].

// out[b] = ||x_dot[b]||^2 + t[b]^2,  t[b] = sum_{i,j} x_dot[b,i] W[i,j] x[b,j]
// k1: block (rg,jc,ic) computes the partial of t[b] over its (i,j) rectangle.
//     jc==0 blocks additionally emit norm partials of x_dot (values already
//     in registers during staging). Deterministic, no atomics, LDS = 40 KB
//     exactly (4 blocks/CU). 4x4 register tile (~80 VGPR; 8x8 spilled in R3).
__global__ __launch_bounds__(256, 4) void stm_main_kernel(
    const float* __restrict__ x, const float* __restrict__ xdot,
    const float* __restrict__ W, float* __restrict__ ws_t) {
  __shared__ float xd_t[ICH][BTILE];   // 8 KB, transposed x_dot chunk [i][b]
  __shared__ float w_s[ICH][JTILE];    // 32 KB W tile

  const int tid = threadIdx.x;
  const int b0 = blockIdx.x * BTILE;
  const int j0 = blockIdx.y * JTILE;
  const int i0 = blockIdx.z * ICH;
  const int tb = tid >> 5;   // 0..7  -> rows b0 + 4*tb .. +3
  const int tj = tid & 31;   // 0..31 -> cols j0 + 4*tj .. +3

  // Stage x_dot chunk transposed: rows b0..b0+31, cols i0..i0+63.
  // Also accumulate this thread's 8 squared elements for the norm.
  float nrm = 0.f;
  {
    const int row = tid & 31;
    const int f4 = tid >> 5;             // 0..7
    const float4* src = (const float4*)(xdot + (size_t)(b0 + row) * DD + i0);
#pragma unroll
    for (int p = 0; p < 2; ++p) {
      const int c4 = f4 + p * 8;         // 0..15
      float4 v = src[c4];
      nrm += v.x * v.x + v.y * v.y + v.z * v.z + v.w * v.w;
      const int c = c4 * 4;
      xd_t[c + 0][row] = v.x; xd_t[c + 1][row] = v.y;
      xd_t[c + 2][row] = v.z; xd_t[c + 3][row] = v.w;
    }
  }
  // Stage W tile: rows i0..i0+63, cols j0..j0+127 (2048 float4 / 256 thr).
  {
#pragma unroll
    for (int v = 0; v < 8; ++v) {
      const int f4 = tid + v * 256;
      const int ii = f4 >> 5, jj4 = f4 & 31;
      *((float4*)&w_s[ii][jj4 * 4]) =
          ((const float4*)(W + (size_t)(i0 + ii) * DD + j0))[jj4];
    }
  }

  // Norm partials: within a wave, lanes l and l+32 cover the same row
  // (row = tid & 31) with disjoint column halves -> one xor-32 fold, then
  // wave w stores rows 0..31 for its column sixteenth. Only jc==0 blocks.
  if (blockIdx.y == 0) {
    nrm += __shfl_xor(nrm, 32);
    const int wv = tid >> 6, ln = tid & 63;
    if (ln < 32)
      ws_t[(size_t)(NTP + blockIdx.z * 4 + wv) * BB + b0 + ln] = nrm;
  }

  // Prefetch epilogue x values so their latency overlaps the FMA loop.
  float4 xv[4];
#pragma unroll
  for (int r = 0; r < 4; ++r)
    xv[r] = ((const float4*)(x + (size_t)(b0 + tb * 4 + r) * DD + j0))[tj];

  __syncthreads();

  // acc[r][c] = sum_i xd[b0+4tb+r, i] * W[i, j0+4tj+c]
  float acc[4][4] = {};
#pragma unroll
  for (int i = 0; i < ICH; ++i) {
    const float4 xd = *(const float4*)&xd_t[i][tb * 4];  // 8 uniq addrs/wave
    const float4 w  = *(const float4*)&w_s[i][tj * 4];
    acc[0][0] += xd.x * w.x; acc[0][1] += xd.x * w.y;
    acc[0][2] += xd.x * w.z; acc[0][3] += xd.x * w.w;
    acc[1][0] += xd.y * w.x; acc[1][1] += xd.y * w.y;
    acc[1][2] += xd.y * w.z; acc[1][3] += xd.y * w.w;
    acc[2][0] += xd.z * w.x; acc[2][1] += xd.z * w.y;
    acc[2][2] += xd.z * w.z; acc[2][3] += xd.z * w.w;
    acc[3][0] += xd.w * w.x; acc[3][1] += xd.w * w.y;
    acc[3][2] += xd.w * w.z; acc[3][3] += xd.w * w.w;
  }

  // Contract with prefetched x, reduce over the 32 tj lanes.
  float tp[4];
#pragma unroll
  for (int r = 0; r < 4; ++r)
    tp[r] = acc[r][0] * xv[r].x + acc[r][1] * xv[r].y +
            acc[r][2] * xv[r].z + acc[r][3] * xv[r].w;
#pragma unroll
  for (int off = 16; off >= 1; off >>= 1) {
#pragma unroll
    for (int r = 0; r < 4; ++r) tp[r] += __shfl_xor(tp[r], off);
  }
  if (tj == 0) {
    const int p = blockIdx.y * NIC + blockIdx.z;   // 0..31
    *(float4*)(ws_t + (size_t)p * BB + b0 + tb * 4) =
        make_float4(tp[0], tp[1], tp[2], tp[3]);
  }
}

// k2: one thread per b. out[b] = (sum norm partials) + (sum t partials)^2.
// 256 KB of partials, L2-resident, fully coalesced across b.
__global__ __launch_bounds__(256) void stm_final_kernel(
    const float* __restrict__ ws_t, float* __restrict__ out) {
  const int b = blockIdx.x * 256 + threadIdx.x;
  float t = 0.f, n = 0.f;
#pragma unroll
  for (int p = 0; p < NTP; ++p) t += ws_t[(size_t)p * BB + b];
#pragma unroll
  for (int p = 0; p < NNP; ++p) n += ws_t[(size_t)(NTP + p) * BB + b];
  out[b] = n + t * t;
}

extern "C" void kernel_launch(void* const* d_in, const int* in_sizes, int n_in,
                              void* d_out, int out_size, void* d_ws, size_t ws_size,
                              hipStream_t stream) {
  const float* x    = (const float*)d_in[0];
  const float* xdot = (const float*)d_in[1];
  const float* W    = (const float*)d_in[2];
  float* ws = (float*)d_ws;   // 64 * 1024 floats = 256 KB of partials
  float* out = (float*)d_out;

  dim3 g1(BB / BTILE, DD / JTILE, NIC);  // (32, 4, 8) = 1024 blocks
  stm_main_kernel<<<g1, 256, 0, stream>>>(x, xdot, W, ws);
  stm_final_kernel<<<BB / 256, 256, 0, stream>>>(ws, out);
}